// Round 10
// baseline (223.651 us; speedup 1.0000x reference)
//
#include <hip/hip_runtime.h>
#include <hip/hip_bf16.h>
#include <math.h>

#define LN_EPS 1e-5f
// Fixed-capacity dst-buckets: bucket = 64 dest nodes, CAP 2048 slots (expected fill ~1024;
// deterministic inputs). pk packs (dstLocal<<20)|src, dstLocal 6 bits, N <= 2^20.
// LESSON (r5): no LDS f32 atomics in per-edge loops. Wave-per-node register agg is right.
// LESSON (r6): agg is latency-bound: pad degree to x8 (dummy row N), lane-coop prefetch +
// readlane scalar-base gathers. ~65us floor at ~72% occupancy.
// LESSON (r8): NO GLOBAL ATOMICS in per-edge loops; block-level reservation atomics OK.
// LESSON (r9): fuse independent partition||gemm in ONE dispatch; agg folds dinv[src] per edge.
// LESSON (r11): csr merged INTO agg (bucket fits LDS) kills the srcidx HBM round-trip.
// LESSON (r14): partition needs MANY medium LDS-buffered blocks co-resident with gemm
// (576-700 blocks), NOT few huge ones (128 blocks -> 10% occupancy disaster).
// LESSON (r15): half-bucket agg blocks re-reading the full bucket pk + 256-wide 16-barrier
// scan cost ~12us vs split agg. Fix: native 64-node buckets (single pk read) + single-wave
// shfl scan. k_init killed: W converted in-gemm, bucketCnt via memset, dummy row in k_deg.
#define CAP 2048
#define CAPSH 11
#define SIDXSZ (CAP + 448)        // padded total <= cntb + 64*7
#define NPBLK 667
#define ECHUNK 2400
#define MAXBUCK 1600

typedef __attribute__((ext_vector_type(8))) short short8;
typedef __attribute__((ext_vector_type(4))) float floatx4;

// ---- FUSED: blocks [0,NPBLK) partition edges; blocks [NPBLK,..) MFMA GEMM (independent) ----
// partition (r5-shape): single pass over ei, LDS edge buffer, block-level reservations.
// gemm: g = bf16(x @ W) UNSCALED -- B staged from W fp32 (convert+transpose in-block, W is
// L2-hot), A fragments direct from global. 32KB LDS union.
__global__ __launch_bounds__(256) void k_part_gemm(const int* __restrict__ ei, int* __restrict__ bucketCnt,
                                                   unsigned* __restrict__ pk, int E, int chunk,
                                                   const float* __restrict__ x, const float* __restrict__ W,
                                                   __hip_bfloat16* __restrict__ g, int N) {
    __shared__ union {
        struct { int ecol[ECHUNK]; int esrc[ECHUNK]; int h[MAXBUCK]; int base[MAXBUCK]; } part;  // 31.25 KB
        unsigned short sB[128 * 128];                                                            // 32 KB
    } u;
    if ((int)blockIdx.x < NPBLK) {
        // ---------------- partition ----------------
        int t = threadIdx.x;
        for (int i = t; i < MAXBUCK; i += 256) u.part.h[i] = 0;
        int e0 = blockIdx.x * chunk;
        int e1 = min(e0 + chunk, E);
        int n = e1 - e0;
        __syncthreads();
        for (int i = t; i < n; i += 256) {
            int col = ei[E + e0 + i];
            u.part.ecol[i] = col;
            u.part.esrc[i] = ei[e0 + i];
            atomicAdd(&u.part.h[col >> 6], 1);
        }
        __syncthreads();
        for (int i = t; i < MAXBUCK; i += 256) {
            if (u.part.h[i] > 0) {
                u.part.base[i] = atomicAdd(&bucketCnt[i], u.part.h[i]);  // block-level reservation
                u.part.h[i] = 0;                                         // reuse as local rank cursor
            }
        }
        __syncthreads();
        for (int i = t; i < n; i += 256) {
            int col = u.part.ecol[i];
            int b = col >> 6;
            int r = u.part.base[b] + atomicAdd(&u.part.h[b], 1);
            if (r < CAP)                                    // overflow guard (never hit; no corruption)
                pk[((unsigned)b << CAPSH) + r] = ((unsigned)(col & 63) << 20) | (unsigned)u.part.esrc[i];
        }
    } else {
        // ---------------- gemm ----------------
        int tid = threadIdx.x;
        int row0 = ((int)blockIdx.x - NPBLK) * 128;
        // stage B: W fp32[k][n] -> sB[n][k] bf16, XOR-swizzled (coalesced reads, scalar LDS writes)
#pragma unroll
        for (int i = 0; i < 16; ++i) {
            int qd = tid + i * 256;                  // 0..4095 float4-quads
            int k = qd >> 5;                         // [0,128)
            int n0 = (qd & 31) * 4;
            float4 w = *(const float4*)(W + (size_t)k * 128 + n0);
            int gq = k >> 3, kj = k & 7;
            u.sB[(n0 + 0) * 128 + ((gq ^ ((n0 + 0) & 15)) << 3) + kj] = (unsigned short)(__bfloat16_as_ushort(__float2bfloat16(w.x)));
            u.sB[(n0 + 1) * 128 + ((gq ^ ((n0 + 1) & 15)) << 3) + kj] = (unsigned short)(__bfloat16_as_ushort(__float2bfloat16(w.y)));
            u.sB[(n0 + 2) * 128 + ((gq ^ ((n0 + 2) & 15)) << 3) + kj] = (unsigned short)(__bfloat16_as_ushort(__float2bfloat16(w.z)));
            u.sB[(n0 + 3) * 128 + ((gq ^ ((n0 + 3) & 15)) << 3) + kj] = (unsigned short)(__bfloat16_as_ushort(__float2bfloat16(w.w)));
        }
        __syncthreads();
        int lane = tid & 63;
        int wv = tid >> 6;
        int m = lane & 15;
        int q = lane >> 4;
        floatx4 acc[2][8];
#pragma unroll
        for (int mt = 0; mt < 2; ++mt)
#pragma unroll
            for (int nt = 0; nt < 8; ++nt) acc[mt][nt] = (floatx4){0.f, 0.f, 0.f, 0.f};
#pragma unroll
        for (int kc = 0; kc < 4; ++kc) {
            int gg = kc * 4 + q;
            short8 afrag[2], bfrag[8];
#pragma unroll
            for (int mt = 0; mt < 2; ++mt) {         // A direct from global (no reuse in block)
                int arow = min(row0 + wv * 32 + mt * 16 + m, N - 1);
                const float* xp = x + (size_t)arow * 128 + gg * 8;
                float4 xa = *(const float4*)xp;
                float4 xb = *(const float4*)(xp + 4);
                union { short8 s; __hip_bfloat16 h[8]; } a;
                a.h[0] = __float2bfloat16(xa.x); a.h[1] = __float2bfloat16(xa.y);
                a.h[2] = __float2bfloat16(xa.z); a.h[3] = __float2bfloat16(xa.w);
                a.h[4] = __float2bfloat16(xb.x); a.h[5] = __float2bfloat16(xb.y);
                a.h[6] = __float2bfloat16(xb.z); a.h[7] = __float2bfloat16(xb.w);
                afrag[mt] = a.s;
            }
#pragma unroll
            for (int nt = 0; nt < 8; ++nt) {
                int n = nt * 16 + m;
                bfrag[nt] = *(const short8*)(&u.sB[n * 128 + ((gg ^ (n & 15)) << 3)]);
            }
#pragma unroll
            for (int mt = 0; mt < 2; ++mt)
#pragma unroll
                for (int nt = 0; nt < 8; ++nt)
                    acc[mt][nt] = __builtin_amdgcn_mfma_f32_16x16x32_bf16(afrag[mt], bfrag[nt], acc[mt][nt], 0, 0, 0);
        }
#pragma unroll
        for (int mt = 0; mt < 2; ++mt) {
#pragma unroll
            for (int i = 0; i < 4; ++i) {
                int row = row0 + wv * 32 + mt * 16 + q * 4 + i;
                if (row < N) {
                    __hip_bfloat16* gp = g + (size_t)row * 128;
#pragma unroll
                    for (int nt = 0; nt < 8; ++nt)
                        gp[nt * 16 + m] = __float2bfloat16(acc[mt][nt][i]);
                }
            }
        }
    }
}

// ---- per-node degree + dinv from pk (one block per 64-node bucket; LDS histogram) ----
// Block 0 also zeroes the dummy g-row N and dinv[N] (pad-edge NaN guard).
__global__ __launch_bounds__(256) void k_deg(const unsigned* __restrict__ pk, const int* __restrict__ bucketCnt,
                                             int* __restrict__ cnt, float* __restrict__ dinv,
                                             unsigned* __restrict__ gdummy, int N) {
    __shared__ int lc[64];
    int b = blockIdx.x;
    int t = threadIdx.x;
    if (t < 64) lc[t] = 0;
    if (b == 0) {
        if (t >= 128 && t < 192) gdummy[t - 128] = 0;   // g row N = 0
        if (t == 192) dinv[N] = 0.f;                    // pad-edge weight = 0
    }
    __syncthreads();
    int ofs = b << CAPSH;
    int cntb = min(bucketCnt[b], CAP);
    for (int e = t; e < cntb; e += 256)
        atomicAdd(&lc[pk[ofs + e] >> 20], 1);
    __syncthreads();
    int node = (b << 6) + t;
    if (t < 64 && node < N) {
        cnt[node] = lc[t];
        dinv[node] = rsqrtf((float)(lc[t] + 1));    // +1 self-loop
    }
}

// ---------- MERGED: bucket LDS-CSR + aggregate + bias + LayerNorm + ReLU ----------
// Block = one 64-node bucket (1563 blocks, ~6/CU). Phase 1: WAVE-0 shfl scan of padded cnt
// (no multi-barrier block scan). Phase 2: scatter bucket's pk into LDS sidx. Phase 3:
// wave-per-node gather (indices from LDS), dinv[src] weight via readlane FMA, LN+ReLU.
#define RLF(V, I) __int_as_float(__builtin_amdgcn_readlane(__float_as_int(V), (I)))

#define LOAD8(P, B) \
    unsigned P##0 = g1[((size_t)(unsigned)__builtin_amdgcn_readlane(myidx, (B) + 0)) * 64u + lane]; \
    unsigned P##1 = g1[((size_t)(unsigned)__builtin_amdgcn_readlane(myidx, (B) + 1)) * 64u + lane]; \
    unsigned P##2 = g1[((size_t)(unsigned)__builtin_amdgcn_readlane(myidx, (B) + 2)) * 64u + lane]; \
    unsigned P##3 = g1[((size_t)(unsigned)__builtin_amdgcn_readlane(myidx, (B) + 3)) * 64u + lane]; \
    unsigned P##4 = g1[((size_t)(unsigned)__builtin_amdgcn_readlane(myidx, (B) + 4)) * 64u + lane]; \
    unsigned P##5 = g1[((size_t)(unsigned)__builtin_amdgcn_readlane(myidx, (B) + 5)) * 64u + lane]; \
    unsigned P##6 = g1[((size_t)(unsigned)__builtin_amdgcn_readlane(myidx, (B) + 6)) * 64u + lane]; \
    unsigned P##7 = g1[((size_t)(unsigned)__builtin_amdgcn_readlane(myidx, (B) + 7)) * 64u + lane];

#define WACC8(P, B) { \
    float w0 = RLF(dlv, (B) + 0), w1 = RLF(dlv, (B) + 1), w2 = RLF(dlv, (B) + 2), w3 = RLF(dlv, (B) + 3); \
    float w4 = RLF(dlv, (B) + 4), w5 = RLF(dlv, (B) + 5), w6 = RLF(dlv, (B) + 6), w7 = RLF(dlv, (B) + 7); \
    ax += ((__uint_as_float(P##0 << 16) * w0 + __uint_as_float(P##1 << 16) * w1) + \
           (__uint_as_float(P##2 << 16) * w2 + __uint_as_float(P##3 << 16) * w3)) + \
          ((__uint_as_float(P##4 << 16) * w4 + __uint_as_float(P##5 << 16) * w5) + \
           (__uint_as_float(P##6 << 16) * w6 + __uint_as_float(P##7 << 16) * w7)); \
    ay += ((__uint_as_float(P##0 & 0xFFFF0000u) * w0 + __uint_as_float(P##1 & 0xFFFF0000u) * w1) + \
           (__uint_as_float(P##2 & 0xFFFF0000u) * w2 + __uint_as_float(P##3 & 0xFFFF0000u) * w3)) + \
          ((__uint_as_float(P##4 & 0xFFFF0000u) * w4 + __uint_as_float(P##5 & 0xFFFF0000u) * w5) + \
           (__uint_as_float(P##6 & 0xFFFF0000u) * w6 + __uint_as_float(P##7 & 0xFFFF0000u) * w7)); }

__global__ __launch_bounds__(256) void k_agg_ln(const __hip_bfloat16* __restrict__ g, const unsigned* __restrict__ pk,
                                                const int* __restrict__ bucketCnt, const int* __restrict__ cnt,
                                                const float* __restrict__ dinv, const float* __restrict__ bias,
                                                const float* __restrict__ gamma, const float* __restrict__ beta,
                                                float* __restrict__ out, int N) {
    __shared__ int sidx[SIDXSZ];    // ~10 KB: bucket's node-grouped src indices
    __shared__ int lofs[64];
    __shared__ int pvs[64];
    __shared__ int lcnt[64];
    int b = blockIdx.x;
    int t = threadIdx.x;
    int lane = t & 63;
    int wv = t >> 6;
    int ofs = b << CAPSH;
    int cntb = min(bucketCnt[b], CAP);
    // ---- phase 1: wave-0 shfl scan of padded per-node counts ----
    if (t < 64) {
        int nd = (b << 6) + lane;
        int v = (nd < N) ? cnt[nd] : 0;
        int pv = (v + 7) & ~7;                  // pad to x8
        int val = pv;
#pragma unroll
        for (int off = 1; off < 64; off <<= 1) {
            int o = __shfl_up(val, off, 64);
            if (lane >= off) val += o;
        }
        int base = val - pv;                    // exclusive
        lofs[lane] = base;
        pvs[lane] = pv;
        lcnt[lane] = 0;
        for (int i = v; i < pv; ++i) {          // pad slots -> dummy row N (dinv[N]=0)
            int sl = base + i;
            if (sl < SIDXSZ) sidx[sl] = N;
        }
    }
    __syncthreads();
    // ---- phase 2: scatter pk into LDS sidx ----
    for (int e = t; e < cntb; e += 256) {
        unsigned u = pk[ofs + e];
        int d = u >> 20;                        // dstLocal in [0,64)
        int r = atomicAdd(&lcnt[d], 1);
        int sl = lofs[d] + r;
        if (sl < SIDXSZ) sidx[sl] = (int)(u & 0xFFFFFu);
    }
    __syncthreads();
    // ---- phase 3: wave-per-node aggregate + LN + ReLU ----
    const unsigned* g1 = (const unsigned*)g;    // u32 = channels {2*lane, 2*lane+1}
    float2 bi = ((const float2*)bias)[lane];
    float2 ga = ((const float2*)gamma)[lane];
    float2 be = ((const float2*)beta)[lane];
    for (int ii = 0; ii < 16; ++ii) {
        int nl = wv * 16 + ii;                  // [0,64)
        int node = (b << 6) + nl;
        if (node >= N) break;                   // wave-uniform
        int startL = lofs[nl];
        int endL = startL + pvs[nl];
        float di = dinv[node];
        unsigned sv = g1[(size_t)node * 64 + lane];
        float ax = __uint_as_float(sv << 16) * di;          // self-loop: dinv[i]*h[i]
        float ay = __uint_as_float(sv & 0xFFFF0000u) * di;
        for (int eb = startL; eb < endL; eb += 64) {
            int myidx = (eb + lane < endL) ? sidx[eb + lane] : N;   // LDS, guarded
            float dlv = dinv[myidx];            // per-edge weight (L2-hot table; dinv[N]=0)
            int nb = min(64, endL - eb);        // multiple of 8
            if (nb >= 24) {                     // issue 24 before first use
                LOAD8(pa, 0)
                LOAD8(pb, 8)
                LOAD8(pc, 16)
                WACC8(pa, 0)
                WACC8(pb, 8)
                WACC8(pc, 16)
                for (int j = 24; j + 8 <= nb; j += 8) {   // deg>24 tail (~2% of nodes)
                    LOAD8(pd, j)
                    WACC8(pd, j)
                }
            } else if (nb == 16) {
                LOAD8(pe, 0)
                LOAD8(pf, 8)
                WACC8(pe, 0)
                WACC8(pf, 8)
            } else {
                LOAD8(pg, 0)
                WACC8(pg, 0)
            }
        }
        float vx = ax * di + bi.x;
        float vy = ay * di + bi.y;
        float sum = vx + vy, sq = vx * vx + vy * vy;
#pragma unroll
        for (int off = 32; off > 0; off >>= 1) {
            sum += __shfl_xor(sum, off, 64);
            sq += __shfl_xor(sq, off, 64);
        }
        float mu = sum * (1.0f / 128.0f);
        float var = sq * (1.0f / 128.0f) - mu * mu;
        float rstd = rsqrtf(var + LN_EPS);
        float o0 = fmaxf((vx - mu) * rstd * ga.x + be.x, 0.f);
        float o1 = fmaxf((vy - mu) * rstd * ga.y + be.y, 0.f);
        ((float2*)out)[(size_t)node * 64 + lane] = make_float2(o0, o1);
    }
}

extern "C" void kernel_launch(void* const* d_in, const int* in_sizes, int n_in,
                              void* d_out, int out_size, void* d_ws, size_t ws_size,
                              hipStream_t stream) {
    const float* x = (const float*)d_in[0];
    const int* ei = (const int*)d_in[1];
    const float* W = (const float*)d_in[2];
    const float* bias = (const float*)d_in[3];
    const float* gamma = (const float*)d_in[4];
    const float* beta = (const float*)d_in[5];
    float* out = (float*)d_out;

    int N = in_sizes[0] / 128;
    int E = in_sizes[1] / 2;
    int NBUCK = (N + 63) / 64;                   // 64-node buckets (1563)

    char* p = (char*)d_ws;
    auto alloc = [&](size_t bytes) {
        char* r = p;
        p += (bytes + 255) & ~(size_t)255;
        return r;
    };
    int* bucketCnt = (int*)alloc(MAXBUCK * 4);
    int* cnt = (int*)alloc((size_t)N * 4);
    float* dinv = (float*)alloc((size_t)(N + 1) * 4);            // +1: dinv[N]=0 pad weight
    unsigned* pk = (unsigned*)alloc((size_t)NBUCK * CAP * 4);    // 12.8MB (ws: agg reads pk while writing d_out)
    __hip_bfloat16* gbuf = (__hip_bfloat16*)alloc((size_t)(N + 1) * 128 * 2);  // +1 dummy zero row

    int chunk = (E + NPBLK - 1) / NPBLK;         // 2399 <= 2400 LDS buffer
    int GB = (N + 127) / 128;

    hipMemsetAsync(bucketCnt, 0, MAXBUCK * 4, stream);
    k_part_gemm<<<NPBLK + GB, 256, 0, stream>>>(ei, bucketCnt, pk, E, chunk, x, W, gbuf, N);
    k_deg<<<NBUCK, 256, 0, stream>>>(pk, bucketCnt, cnt, dinv, (unsigned*)(gbuf + (size_t)N * 128), N);
    k_agg_ln<<<NBUCK, 256, 0, stream>>>(gbuf, pk, bucketCnt, cnt, dinv, bias, gamma, beta, out, N);
}

// Round 11
// 222.060 us; speedup vs baseline: 1.0072x; 1.0072x over previous
//
#include <hip/hip_runtime.h>
#include <hip/hip_bf16.h>
#include <math.h>

#define LN_EPS 1e-5f
// Fixed-capacity dst-buckets: bucket = 128 dest nodes, CAP 4096 (expected fill ~2050;
// deterministic inputs). pk packs (dstLocal<<20)|src, dstLocal 7 bits, N <= 2^20.
// LESSON (r5): no LDS f32 atomics in per-edge loops. Wave-per-node register agg is right.
// LESSON (r6): agg is latency-bound; pad degree to x8 (dummy row N), lane-coop prefetch +
// readlane scalar-base gathers.
// LESSON (r8): NO GLOBAL ATOMICS in per-edge loops; block-level reservation atomics OK.
// LESSON (r9): fuse independent partition||gemm in ONE dispatch; agg folds dinv[src] per edge.
// LESSON (r11): csr merged INTO agg (bucket fits LDS) kills the srcidx HBM round-trip.
// LESSON (r14): partition needs MANY medium LDS-buffered blocks (~576), not few huge ones.
// LESSON (r16): 64-node buckets double partition write-amp (667x1563 lines = 67MB vs
// 576x782 = 29MB): partition wants BIG buckets, agg wants MANY blocks. Decouple via agg
// BLOCK SIZE: 128-node buckets + 512-thread agg blocks (782 x 8 waves = 75% occ ceiling,
// vs r6's 37% at 256 thr). W-conv back in k_init (in-gemm scalar LDS writes bank-serialize).
#define CAP 4096
#define CAPSH 12
#define SIDXSZ (CAP + 896)        // padded total <= cntb + 128*7
#define NPBLK 576
#define ECHUNK 2816
#define MAXBUCK 800

typedef __attribute__((ext_vector_type(8))) short short8;
typedef __attribute__((ext_vector_type(4))) float floatx4;

// ---- tiny init: W fp32[k][n] -> bf16 Wt[n][k]; zero bucketCnt, dummy g-row, dinv[N] ----
__global__ __launch_bounds__(256) void k_init(const float* __restrict__ W, __hip_bfloat16* __restrict__ Wt,
                                              int* __restrict__ bucketCnt, unsigned* __restrict__ gdummy,
                                              float* __restrict__ dinv, int N) {
    int t = threadIdx.x;
    int i = blockIdx.x * 256 + t;               // 64 blocks x 256 = 16384
    int n = i >> 7, k = i & 127;
    Wt[i] = __float2bfloat16(W[k * 128 + n]);
    if (blockIdx.x == 0) {
        for (int j = t; j < MAXBUCK; j += 256) bucketCnt[j] = 0;
        if (t < 64) gdummy[t] = 0;              // g row N = 0 (pad-edge target)
        if (t == 0) dinv[N] = 0.f;              // pad-edge weight = 0 (NaN guard)
    }
}

// ---- FUSED: blocks [0,NPBLK) partition edges; blocks [NPBLK,..) MFMA GEMM (independent) ----
// partition (r9-proven): single pass over ei, LDS edge buffer, block-level reservations.
// gemm: g = bf16(x @ W) UNSCALED -- B tile LDS-staged+swizzled, A fragments direct from global.
__global__ __launch_bounds__(256) void k_part_gemm(const int* __restrict__ ei, int* __restrict__ bucketCnt,
                                                   unsigned* __restrict__ pk, int E, int chunk,
                                                   const float* __restrict__ x, const __hip_bfloat16* __restrict__ Wt,
                                                   __hip_bfloat16* __restrict__ g, int N) {
    __shared__ union {
        struct { int ecol[ECHUNK]; int esrc[ECHUNK]; int h[MAXBUCK]; int base[MAXBUCK]; } part;  // 28.3 KB
        unsigned short sB[128 * 128];                                                            // 32 KB
    } u;
    if ((int)blockIdx.x < NPBLK) {
        // ---------------- partition ----------------
        int t = threadIdx.x;
        for (int i = t; i < MAXBUCK; i += 256) u.part.h[i] = 0;
        int e0 = blockIdx.x * chunk;
        int e1 = min(e0 + chunk, E);
        int n = e1 - e0;
        __syncthreads();
        for (int i = t; i < n; i += 256) {
            int col = ei[E + e0 + i];
            u.part.ecol[i] = col;
            u.part.esrc[i] = ei[e0 + i];
            atomicAdd(&u.part.h[col >> 7], 1);
        }
        __syncthreads();
        for (int i = t; i < MAXBUCK; i += 256) {
            if (u.part.h[i] > 0) {
                u.part.base[i] = atomicAdd(&bucketCnt[i], u.part.h[i]);  // block-level reservation
                u.part.h[i] = 0;                                         // reuse as local rank cursor
            }
        }
        __syncthreads();
        for (int i = t; i < n; i += 256) {
            int col = u.part.ecol[i];
            int b = col >> 7;
            int r = u.part.base[b] + atomicAdd(&u.part.h[b], 1);
            if (r < CAP)                                    // overflow guard (never hit; no corruption)
                pk[((unsigned)b << CAPSH) + r] = ((unsigned)(col & 127) << 20) | (unsigned)u.part.esrc[i];
        }
    } else {
        // ---------------- gemm ----------------
        int tid = threadIdx.x;
        int row0 = ((int)blockIdx.x - NPBLK) * 128;
#pragma unroll
        for (int i = 0; i < 8; ++i) {                // stage B only: 16384 shorts / 256 thr
            int idx = tid + i * 256;                 // 0..2047
            int row = idx >> 4;
            int gr = idx & 15;
            int grs = gr ^ (row & 15);
            *(short8*)(&u.sB[row * 128 + grs * 8]) = *(const short8*)(Wt + (size_t)row * 128 + gr * 8);
        }
        __syncthreads();
        int lane = tid & 63;
        int wv = tid >> 6;
        int m = lane & 15;
        int q = lane >> 4;
        floatx4 acc[2][8];
#pragma unroll
        for (int mt = 0; mt < 2; ++mt)
#pragma unroll
            for (int nt = 0; nt < 8; ++nt) acc[mt][nt] = (floatx4){0.f, 0.f, 0.f, 0.f};
#pragma unroll
        for (int kc = 0; kc < 4; ++kc) {
            int gg = kc * 4 + q;
            short8 afrag[2], bfrag[8];
#pragma unroll
            for (int mt = 0; mt < 2; ++mt) {         // A direct from global (no reuse in block)
                int arow = min(row0 + wv * 32 + mt * 16 + m, N - 1);
                const float* xp = x + (size_t)arow * 128 + gg * 8;
                float4 xa = *(const float4*)xp;
                float4 xb = *(const float4*)(xp + 4);
                union { short8 s; __hip_bfloat16 h[8]; } a;
                a.h[0] = __float2bfloat16(xa.x); a.h[1] = __float2bfloat16(xa.y);
                a.h[2] = __float2bfloat16(xa.z); a.h[3] = __float2bfloat16(xa.w);
                a.h[4] = __float2bfloat16(xb.x); a.h[5] = __float2bfloat16(xb.y);
                a.h[6] = __float2bfloat16(xb.z); a.h[7] = __float2bfloat16(xb.w);
                afrag[mt] = a.s;
            }
#pragma unroll
            for (int nt = 0; nt < 8; ++nt) {
                int n = nt * 16 + m;
                bfrag[nt] = *(const short8*)(&u.sB[n * 128 + (gg ^ (n & 15)) * 8]);
            }
#pragma unroll
            for (int mt = 0; mt < 2; ++mt)
#pragma unroll
                for (int nt = 0; nt < 8; ++nt)
                    acc[mt][nt] = __builtin_amdgcn_mfma_f32_16x16x32_bf16(afrag[mt], bfrag[nt], acc[mt][nt], 0, 0, 0);
        }
#pragma unroll
        for (int mt = 0; mt < 2; ++mt) {
#pragma unroll
            for (int i = 0; i < 4; ++i) {
                int row = row0 + wv * 32 + mt * 16 + q * 4 + i;
                if (row < N) {
                    __hip_bfloat16* gp = g + (size_t)row * 128;
#pragma unroll
                    for (int nt = 0; nt < 8; ++nt)
                        gp[nt * 16 + m] = __float2bfloat16(acc[mt][nt][i]);
                }
            }
        }
    }
}

// ---- per-node degree + dinv from pk (one block per 128-node bucket; LDS histogram) ----
__global__ __launch_bounds__(256) void k_deg(const unsigned* __restrict__ pk, const int* __restrict__ bucketCnt,
                                             int* __restrict__ cnt, float* __restrict__ dinv, int N) {
    __shared__ int lc[128];
    int b = blockIdx.x;
    int t = threadIdx.x;
    if (t < 128) lc[t] = 0;
    __syncthreads();
    int ofs = b << CAPSH;
    int cntb = min(bucketCnt[b], CAP);
    for (int e = t; e < cntb; e += 256)
        atomicAdd(&lc[pk[ofs + e] >> 20], 1);
    __syncthreads();
    int node = (b << 7) + t;
    if (t < 128 && node < N) {
        cnt[node] = lc[t];
        dinv[node] = rsqrtf((float)(lc[t] + 1));    // +1 self-loop
    }
}

// ---------- MERGED: bucket LDS-CSR + aggregate + bias + LayerNorm + ReLU (512 thr) ----------
// Block = one 128-node bucket, 8 waves (782 blocks x 8 = 75% occ ceiling at 3 blk/CU).
// Phase 1: 2-wave shfl scan of padded cnt (+ cross-wave fixup). Phase 2: scatter pk into
// LDS sidx (stride 512). Phase 3: wave-per-node gather, dinv[src] readlane FMA, LN+ReLU.
#define RLF(V, I) __int_as_float(__builtin_amdgcn_readlane(__float_as_int(V), (I)))

#define LOAD8(P, B) \
    unsigned P##0 = g1[((size_t)(unsigned)__builtin_amdgcn_readlane(myidx, (B) + 0)) * 64u + lane]; \
    unsigned P##1 = g1[((size_t)(unsigned)__builtin_amdgcn_readlane(myidx, (B) + 1)) * 64u + lane]; \
    unsigned P##2 = g1[((size_t)(unsigned)__builtin_amdgcn_readlane(myidx, (B) + 2)) * 64u + lane]; \
    unsigned P##3 = g1[((size_t)(unsigned)__builtin_amdgcn_readlane(myidx, (B) + 3)) * 64u + lane]; \
    unsigned P##4 = g1[((size_t)(unsigned)__builtin_amdgcn_readlane(myidx, (B) + 4)) * 64u + lane]; \
    unsigned P##5 = g1[((size_t)(unsigned)__builtin_amdgcn_readlane(myidx, (B) + 5)) * 64u + lane]; \
    unsigned P##6 = g1[((size_t)(unsigned)__builtin_amdgcn_readlane(myidx, (B) + 6)) * 64u + lane]; \
    unsigned P##7 = g1[((size_t)(unsigned)__builtin_amdgcn_readlane(myidx, (B) + 7)) * 64u + lane];

#define WACC8(P, B) { \
    float w0 = RLF(dlv, (B) + 0), w1 = RLF(dlv, (B) + 1), w2 = RLF(dlv, (B) + 2), w3 = RLF(dlv, (B) + 3); \
    float w4 = RLF(dlv, (B) + 4), w5 = RLF(dlv, (B) + 5), w6 = RLF(dlv, (B) + 6), w7 = RLF(dlv, (B) + 7); \
    ax += ((__uint_as_float(P##0 << 16) * w0 + __uint_as_float(P##1 << 16) * w1) + \
           (__uint_as_float(P##2 << 16) * w2 + __uint_as_float(P##3 << 16) * w3)) + \
          ((__uint_as_float(P##4 << 16) * w4 + __uint_as_float(P##5 << 16) * w5) + \
           (__uint_as_float(P##6 << 16) * w6 + __uint_as_float(P##7 << 16) * w7)); \
    ay += ((__uint_as_float(P##0 & 0xFFFF0000u) * w0 + __uint_as_float(P##1 & 0xFFFF0000u) * w1) + \
           (__uint_as_float(P##2 & 0xFFFF0000u) * w2 + __uint_as_float(P##3 & 0xFFFF0000u) * w3)) + \
          ((__uint_as_float(P##4 & 0xFFFF0000u) * w4 + __uint_as_float(P##5 & 0xFFFF0000u) * w5) + \
           (__uint_as_float(P##6 & 0xFFFF0000u) * w6 + __uint_as_float(P##7 & 0xFFFF0000u) * w7)); }

__global__ __launch_bounds__(512) void k_agg_ln(const __hip_bfloat16* __restrict__ g, const unsigned* __restrict__ pk,
                                                const int* __restrict__ bucketCnt, const int* __restrict__ cnt,
                                                const float* __restrict__ dinv, const float* __restrict__ bias,
                                                const float* __restrict__ gamma, const float* __restrict__ beta,
                                                float* __restrict__ out, int N) {
    __shared__ int sidx[SIDXSZ];    // ~19.5 KB: bucket's node-grouped src indices
    __shared__ int lofs[128];
    __shared__ int pvs[128];
    __shared__ int lcnt[128];
    __shared__ int wsum[2];
    int b = blockIdx.x;
    int t = threadIdx.x;
    int lane = t & 63;
    int wvid = t >> 6;              // 0..7
    int ofs = b << CAPSH;
    int cntb = min(bucketCnt[b], CAP);
    // ---- phase 1: 2-wave shfl scan of padded per-node counts ----
    int v = 0, pv = 0, val = 0;
    if (t < 128) {
        int nd = (b << 7) + t;
        v = (nd < N) ? cnt[nd] : 0;
        pv = (v + 7) & ~7;                      // pad to x8
        val = pv;
#pragma unroll
        for (int off = 1; off < 64; off <<= 1) {
            int o = __shfl_up(val, off, 64);
            if (lane >= off) val += o;
        }
        if (lane == 63) wsum[wvid] = val;       // wvid 0 or 1
    }
    __syncthreads();
    if (t < 128) {
        int base = val - pv + ((t >= 64) ? wsum[0] : 0);    // exclusive, cross-wave fixed
        lofs[t] = base;
        pvs[t] = pv;
        lcnt[t] = 0;
        for (int i = v; i < pv; ++i) {          // pad slots -> dummy row N (dinv[N]=0)
            int sl = base + i;
            if (sl < SIDXSZ) sidx[sl] = N;
        }
    }
    __syncthreads();
    // ---- phase 2: scatter pk into LDS sidx ----
    for (int e = t; e < cntb; e += 512) {
        unsigned u = pk[ofs + e];
        int d = u >> 20;                        // dstLocal in [0,128)
        int r = atomicAdd(&lcnt[d], 1);
        int sl = lofs[d] + r;
        if (sl < SIDXSZ) sidx[sl] = (int)(u & 0xFFFFFu);
    }
    __syncthreads();
    // ---- phase 3: wave-per-node aggregate + LN + ReLU (8 waves x 16 nodes) ----
    const unsigned* g1 = (const unsigned*)g;    // u32 = channels {2*lane, 2*lane+1}
    float2 bi = ((const float2*)bias)[lane];
    float2 ga = ((const float2*)gamma)[lane];
    float2 be = ((const float2*)beta)[lane];
    for (int ii = 0; ii < 16; ++ii) {
        int nl = wvid * 16 + ii;                // [0,128)
        int node = (b << 7) + nl;
        if (node >= N) break;                   // wave-uniform
        int startL = lofs[nl];
        int endL = startL + pvs[nl];
        float di = dinv[node];
        unsigned sv = g1[(size_t)node * 64 + lane];
        float ax = __uint_as_float(sv << 16) * di;          // self-loop: dinv[i]*h[i]
        float ay = __uint_as_float(sv & 0xFFFF0000u) * di;
        for (int eb = startL; eb < endL; eb += 64) {
            int myidx = (eb + lane < endL) ? sidx[eb + lane] : N;   // LDS, guarded
            float dlv = dinv[myidx];            // per-edge weight (L2-hot table; dinv[N]=0)
            int nb = min(64, endL - eb);        // multiple of 8
            if (nb >= 24) {                     // issue 24 before first use
                LOAD8(pa, 0)
                LOAD8(pb, 8)
                LOAD8(pc, 16)
                WACC8(pa, 0)
                WACC8(pb, 8)
                WACC8(pc, 16)
                for (int j = 24; j + 8 <= nb; j += 8) {   // deg>24 tail (~2% of nodes)
                    LOAD8(pd, j)
                    WACC8(pd, j)
                }
            } else if (nb == 16) {
                LOAD8(pe, 0)
                LOAD8(pf, 8)
                WACC8(pe, 0)
                WACC8(pf, 8)
            } else {
                LOAD8(pg, 0)
                WACC8(pg, 0)
            }
        }
        float vx = ax * di + bi.x;
        float vy = ay * di + bi.y;
        float sum = vx + vy, sq = vx * vx + vy * vy;
#pragma unroll
        for (int off = 32; off > 0; off >>= 1) {
            sum += __shfl_xor(sum, off, 64);
            sq += __shfl_xor(sq, off, 64);
        }
        float mu = sum * (1.0f / 128.0f);
        float var = sq * (1.0f / 128.0f) - mu * mu;
        float rstd = rsqrtf(var + LN_EPS);
        float o0 = fmaxf((vx - mu) * rstd * ga.x + be.x, 0.f);
        float o1 = fmaxf((vy - mu) * rstd * ga.y + be.y, 0.f);
        ((float2*)out)[(size_t)node * 64 + lane] = make_float2(o0, o1);
    }
}

extern "C" void kernel_launch(void* const* d_in, const int* in_sizes, int n_in,
                              void* d_out, int out_size, void* d_ws, size_t ws_size,
                              hipStream_t stream) {
    const float* x = (const float*)d_in[0];
    const int* ei = (const int*)d_in[1];
    const float* W = (const float*)d_in[2];
    const float* bias = (const float*)d_in[3];
    const float* gamma = (const float*)d_in[4];
    const float* beta = (const float*)d_in[5];
    float* out = (float*)d_out;

    int N = in_sizes[0] / 128;
    int E = in_sizes[1] / 2;
    int NBUCK = (N + 127) / 128;                 // 128-node buckets (782)

    char* p = (char*)d_ws;
    auto alloc = [&](size_t bytes) {
        char* r = p;
        p += (bytes + 255) & ~(size_t)255;
        return r;
    };
    int* bucketCnt = (int*)alloc(MAXBUCK * 4);
    int* cnt = (int*)alloc((size_t)N * 4);
    float* dinv = (float*)alloc((size_t)(N + 1) * 4);            // +1: dinv[N]=0 pad weight
    __hip_bfloat16* Wt = (__hip_bfloat16*)alloc(128 * 128 * 2);
    unsigned* pk = (unsigned*)alloc((size_t)NBUCK * CAP * 4);    // 12.8MB (ws: agg reads pk while writing d_out)
    __hip_bfloat16* gbuf = (__hip_bfloat16*)alloc((size_t)(N + 1) * 128 * 2);  // +1 dummy zero row

    int chunk = (E + NPBLK - 1) / NPBLK;         // 2778 <= 2816 LDS buffer
    int GB = (N + 127) / 128;

    k_init<<<64, 256, 0, stream>>>(W, Wt, bucketCnt, (unsigned*)(gbuf + (size_t)N * 128), dinv, N);
    k_part_gemm<<<NPBLK + GB, 256, 0, stream>>>(ei, bucketCnt, pk, E, chunk, x, Wt, gbuf, N);
    k_deg<<<NBUCK, 256, 0, stream>>>(pk, bucketCnt, cnt, dinv, N);
    k_agg_ln<<<NBUCK, 512, 0, stream>>>(gbuf, pk, bucketCnt, cnt, dinv, bias, gamma, beta, out, N);
}

// Round 12
// 212.378 us; speedup vs baseline: 1.0531x; 1.0456x over previous
//
#include <hip/hip_runtime.h>
#include <hip/hip_bf16.h>
#include <math.h>

#define LN_EPS 1e-5f
// Fixed-capacity dst-buckets: bucket = 128 dest nodes, CAP 4096 (expected fill ~2050;
// deterministic inputs). pk packs (dstLocal<<20)|src, dstLocal 7 bits, N <= 2^20.
// LESSON (r5): no LDS f32 atomics in per-edge loops. Wave-per-node register agg is right.
// LESSON (r6): agg is latency-bound; pad degree to x8 (dummy row N), lane-coop prefetch +
// readlane scalar-base gathers. ~65us at 72% occupancy = L3-random floor for this decomp.
// LESSON (r8): NO GLOBAL ATOMICS in per-edge loops; block-level reservation atomics OK.
// LESSON (r9): fuse independent partition||gemm in ONE dispatch; agg folds dinv[src] per edge.
// LESSON (r14): partition needs MANY medium LDS-buffered blocks (~576), not few huge ones.
// LESSON (r16): 64-node buckets double partition write-amp; partition wants BIG buckets.
// LESSON (r17): merged-agg direction EXHAUSTED (6 variants, best 212.6 vs split 211.6):
// split agg's 100K independent 1-node waves hide L3 latency better than any per-bucket
// phase-barrier structure (best merged: 72.3us agg vs split 65us). Keep r5 split pipeline;
// optimize csr instead: 512 threads + 2-wave shfl scan (kill 16-barrier block scan).
#define CAP 4096
#define CAPSH 12
#define NPBLK 576
#define ECHUNK 2816
#define MAXBUCK 800

typedef __attribute__((ext_vector_type(8))) short short8;
typedef __attribute__((ext_vector_type(4))) float floatx4;

// ---- tiny init: W fp32[k][n] -> bf16 Wt[n][k]; zero bucketCnt, dummy g-row, dinv[N] ----
__global__ __launch_bounds__(256) void k_init(const float* __restrict__ W, __hip_bfloat16* __restrict__ Wt,
                                              int* __restrict__ bucketCnt, unsigned* __restrict__ gdummy,
                                              float* __restrict__ dinv, int N) {
    int t = threadIdx.x;
    int i = blockIdx.x * 256 + t;               // 64 blocks x 256 = 16384
    int n = i >> 7, k = i & 127;
    Wt[i] = __float2bfloat16(W[k * 128 + n]);
    if (blockIdx.x == 0) {
        for (int j = t; j < MAXBUCK; j += 256) bucketCnt[j] = 0;
        if (t < 64) gdummy[t] = 0;              // g row N = 0 (pad-edge target)
        if (t == 0) dinv[N] = 0.f;              // pad-edge weight = 0 (NaN guard)
    }
}

// ---- FUSED: blocks [0,NPBLK) partition edges; blocks [NPBLK,..) MFMA GEMM (independent) ----
// partition (r5-proven): single pass over ei, LDS edge buffer, block-level reservations.
// gemm: g = bf16(x @ W) UNSCALED -- B tile LDS-staged+swizzled, A fragments direct from global.
__global__ __launch_bounds__(256) void k_part_gemm(const int* __restrict__ ei, int* __restrict__ bucketCnt,
                                                   unsigned* __restrict__ pk, int E, int chunk,
                                                   const float* __restrict__ x, const __hip_bfloat16* __restrict__ Wt,
                                                   __hip_bfloat16* __restrict__ g, int N) {
    __shared__ union {
        struct { int ecol[ECHUNK]; int esrc[ECHUNK]; int h[MAXBUCK]; int base[MAXBUCK]; } part;  // 28.3 KB
        unsigned short sB[128 * 128];                                                            // 32 KB
    } u;
    if ((int)blockIdx.x < NPBLK) {
        // ---------------- partition ----------------
        int t = threadIdx.x;
        for (int i = t; i < MAXBUCK; i += 256) u.part.h[i] = 0;
        int e0 = blockIdx.x * chunk;
        int e1 = min(e0 + chunk, E);
        int n = e1 - e0;
        __syncthreads();
        for (int i = t; i < n; i += 256) {
            int col = ei[E + e0 + i];
            u.part.ecol[i] = col;
            u.part.esrc[i] = ei[e0 + i];
            atomicAdd(&u.part.h[col >> 7], 1);
        }
        __syncthreads();
        for (int i = t; i < MAXBUCK; i += 256) {
            if (u.part.h[i] > 0) {
                u.part.base[i] = atomicAdd(&bucketCnt[i], u.part.h[i]);  // block-level reservation
                u.part.h[i] = 0;                                         // reuse as local rank cursor
            }
        }
        __syncthreads();
        for (int i = t; i < n; i += 256) {
            int col = u.part.ecol[i];
            int b = col >> 7;
            int r = u.part.base[b] + atomicAdd(&u.part.h[b], 1);
            if (r < CAP)                                    // overflow guard (never hit; no corruption)
                pk[((unsigned)b << CAPSH) + r] = ((unsigned)(col & 127) << 20) | (unsigned)u.part.esrc[i];
        }
    } else {
        // ---------------- gemm ----------------
        int tid = threadIdx.x;
        int row0 = ((int)blockIdx.x - NPBLK) * 128;
#pragma unroll
        for (int i = 0; i < 8; ++i) {                // stage B only: 16384 shorts / 256 thr
            int idx = tid + i * 256;                 // 0..2047
            int row = idx >> 4;
            int gr = idx & 15;
            int grs = gr ^ (row & 15);
            *(short8*)(&u.sB[row * 128 + grs * 8]) = *(const short8*)(Wt + (size_t)row * 128 + gr * 8);
        }
        __syncthreads();
        int lane = tid & 63;
        int wv = tid >> 6;
        int m = lane & 15;
        int q = lane >> 4;
        floatx4 acc[2][8];
#pragma unroll
        for (int mt = 0; mt < 2; ++mt)
#pragma unroll
            for (int nt = 0; nt < 8; ++nt) acc[mt][nt] = (floatx4){0.f, 0.f, 0.f, 0.f};
#pragma unroll
        for (int kc = 0; kc < 4; ++kc) {
            int gg = kc * 4 + q;
            short8 afrag[2], bfrag[8];
#pragma unroll
            for (int mt = 0; mt < 2; ++mt) {         // A direct from global (no reuse in block)
                int arow = min(row0 + wv * 32 + mt * 16 + m, N - 1);
                const float* xp = x + (size_t)arow * 128 + gg * 8;
                float4 xa = *(const float4*)xp;
                float4 xb = *(const float4*)(xp + 4);
                union { short8 s; __hip_bfloat16 h[8]; } a;
                a.h[0] = __float2bfloat16(xa.x); a.h[1] = __float2bfloat16(xa.y);
                a.h[2] = __float2bfloat16(xa.z); a.h[3] = __float2bfloat16(xa.w);
                a.h[4] = __float2bfloat16(xb.x); a.h[5] = __float2bfloat16(xb.y);
                a.h[6] = __float2bfloat16(xb.z); a.h[7] = __float2bfloat16(xb.w);
                afrag[mt] = a.s;
            }
#pragma unroll
            for (int nt = 0; nt < 8; ++nt) {
                int n = nt * 16 + m;
                bfrag[nt] = *(const short8*)(&u.sB[n * 128 + (gg ^ (n & 15)) * 8]);
            }
#pragma unroll
            for (int mt = 0; mt < 2; ++mt)
#pragma unroll
                for (int nt = 0; nt < 8; ++nt)
                    acc[mt][nt] = __builtin_amdgcn_mfma_f32_16x16x32_bf16(afrag[mt], bfrag[nt], acc[mt][nt], 0, 0, 0);
        }
#pragma unroll
        for (int mt = 0; mt < 2; ++mt) {
#pragma unroll
            for (int i = 0; i < 4; ++i) {
                int row = row0 + wv * 32 + mt * 16 + q * 4 + i;
                if (row < N) {
                    __hip_bfloat16* gp = g + (size_t)row * 128;
#pragma unroll
                    for (int nt = 0; nt < 8; ++nt)
                        gp[nt * 16 + m] = __float2bfloat16(acc[mt][nt][i]);
                }
            }
        }
    }
}

// ---- bucket -> CSR (512 thr, LDS-staged pk, 2-wave shfl scan) + rowcnt/dinv; pads to x8 ----
__global__ __launch_bounds__(512) void k_csr(const unsigned* __restrict__ pk, const int* __restrict__ bucketCnt,
                                             int2* __restrict__ rowcnt, float* __restrict__ dinv,
                                             int* __restrict__ srcidx, int N) {
    __shared__ unsigned spk[CAP];                // 16 KB stage (single global read of bucket)
    __shared__ int lcnt[128];
    __shared__ int lofs[128];
    __shared__ int pvs[128];
    __shared__ int wsum[2];
    int b = blockIdx.x;
    int t = threadIdx.x;
    int lane = t & 63;
    int wvid = t >> 6;
    int ofs = b << CAPSH;
    int cntb = min(bucketCnt[b], CAP);
    if (t < 128) lcnt[t] = 0;
    __syncthreads();
    for (int e = t; e < cntb; e += 512) {        // stage + histogram
        unsigned v = pk[ofs + e];
        spk[e] = v;
        atomicAdd(&lcnt[v >> 20], 1);            // dstLocal in [0,128)
    }
    __syncthreads();
    // 2-wave shfl scan of padded counts (threads [0,128) = waves 0,1)
    int v = 0, pv = 0, val = 0;
    if (t < 128) {
        v = lcnt[t];
        pv = (v + 7) & ~7;                       // pad to x8
        val = pv;
#pragma unroll
        for (int off = 1; off < 64; off <<= 1) {
            int o = __shfl_up(val, off, 64);
            if (lane >= off) val += o;
        }
        if (lane == 63) wsum[wvid] = val;
    }
    __syncthreads();
    if (t < 128) {
        int base = val - pv + ((t >= 64) ? wsum[0] : 0);   // exclusive, cross-wave fixed
        lofs[t] = base;
        pvs[t] = pv;
        int node = (b << 7) + t;
        if (node < N) {
            rowcnt[node] = make_int2(ofs + base, pv);
            dinv[node] = rsqrtf((float)(v + 1));     // +1 self-loop (actual degree)
            for (int i = v; i < pv; ++i) {           // pad slots -> dummy row N (dinv[N]=0)
                int sl = base + i;
                if (sl < CAP) srcidx[ofs + sl] = N;
            }
        }
        lcnt[t] = 0;                             // reuse as scatter cursor
    }
    __syncthreads();
    for (int e = t; e < cntb; e += 512) {        // scatter from LDS stage
        unsigned pvv = spk[e];
        int d = pvv >> 20;
        int r = atomicAdd(&lcnt[d], 1);
        int sl = lofs[d] + r;
        if (sl < CAP) srcidx[ofs + sl] = (int)(pvv & 0xFFFFFu);
    }
}

// ---------- fused aggregate + bias + LayerNorm + ReLU (bf16 gather, wave-per-node) ----------
// Lane-coop srcidx prefetch; per-edge weight dinv[src] gathered per lane (L2-hot 400KB table),
// broadcast via readlane, FMA-accumulated. Degree padded to x8 (dummy zero row N, dinv[N]=0).
#define RLF(V, I) __int_as_float(__builtin_amdgcn_readlane(__float_as_int(V), (I)))

#define LOAD8(P, B) \
    unsigned P##0 = g1[((size_t)(unsigned)__builtin_amdgcn_readlane(myidx, (B) + 0)) * 64u + lane]; \
    unsigned P##1 = g1[((size_t)(unsigned)__builtin_amdgcn_readlane(myidx, (B) + 1)) * 64u + lane]; \
    unsigned P##2 = g1[((size_t)(unsigned)__builtin_amdgcn_readlane(myidx, (B) + 2)) * 64u + lane]; \
    unsigned P##3 = g1[((size_t)(unsigned)__builtin_amdgcn_readlane(myidx, (B) + 3)) * 64u + lane]; \
    unsigned P##4 = g1[((size_t)(unsigned)__builtin_amdgcn_readlane(myidx, (B) + 4)) * 64u + lane]; \
    unsigned P##5 = g1[((size_t)(unsigned)__builtin_amdgcn_readlane(myidx, (B) + 5)) * 64u + lane]; \
    unsigned P##6 = g1[((size_t)(unsigned)__builtin_amdgcn_readlane(myidx, (B) + 6)) * 64u + lane]; \
    unsigned P##7 = g1[((size_t)(unsigned)__builtin_amdgcn_readlane(myidx, (B) + 7)) * 64u + lane];

#define WACC8(P, B) { \
    float w0 = RLF(dlv, (B) + 0), w1 = RLF(dlv, (B) + 1), w2 = RLF(dlv, (B) + 2), w3 = RLF(dlv, (B) + 3); \
    float w4 = RLF(dlv, (B) + 4), w5 = RLF(dlv, (B) + 5), w6 = RLF(dlv, (B) + 6), w7 = RLF(dlv, (B) + 7); \
    ax += ((__uint_as_float(P##0 << 16) * w0 + __uint_as_float(P##1 << 16) * w1) + \
           (__uint_as_float(P##2 << 16) * w2 + __uint_as_float(P##3 << 16) * w3)) + \
          ((__uint_as_float(P##4 << 16) * w4 + __uint_as_float(P##5 << 16) * w5) + \
           (__uint_as_float(P##6 << 16) * w6 + __uint_as_float(P##7 << 16) * w7)); \
    ay += ((__uint_as_float(P##0 & 0xFFFF0000u) * w0 + __uint_as_float(P##1 & 0xFFFF0000u) * w1) + \
           (__uint_as_float(P##2 & 0xFFFF0000u) * w2 + __uint_as_float(P##3 & 0xFFFF0000u) * w3)) + \
          ((__uint_as_float(P##4 & 0xFFFF0000u) * w4 + __uint_as_float(P##5 & 0xFFFF0000u) * w5) + \
           (__uint_as_float(P##6 & 0xFFFF0000u) * w6 + __uint_as_float(P##7 & 0xFFFF0000u) * w7)); }

__global__ __launch_bounds__(256) void k_agg_ln(const __hip_bfloat16* __restrict__ g, const int* __restrict__ srcidx,
                                                const int2* __restrict__ rowcnt,
                                                const float* __restrict__ dinv, const float* __restrict__ bias,
                                                const float* __restrict__ gamma, const float* __restrict__ beta,
                                                float* __restrict__ out, int N) {
    int wid = (int)((blockIdx.x * 256u + threadIdx.x) >> 6);
    int lane = threadIdx.x & 63;
    if (wid >= N) return;
    const unsigned* g1 = (const unsigned*)g;     // u32 = channels {2*lane, 2*lane+1}
    float di = dinv[wid];
    unsigned sv = g1[(size_t)wid * 64 + lane];
    float ax = __uint_as_float(sv << 16) * di;          // self-loop term: dinv[i]*h[i]
    float ay = __uint_as_float(sv & 0xFFFF0000u) * di;
    int2 rc = rowcnt[wid];
    int start = __builtin_amdgcn_readfirstlane(rc.x);
    int pcnt = __builtin_amdgcn_readfirstlane(rc.y);    // padded, multiple of 8
    int end = start + pcnt;
    for (int eb = start; eb < end; eb += 64) {
        int myidx = srcidx[eb + lane];            // coalesced 64-index prefetch (slack-guarded alloc)
        if (eb + lane >= end) myidx = N;          // sanitize: garbage would index dinv OOB
        float dlv = dinv[myidx];                  // per-edge weight (L2-hot table; dinv[N]=0)
        int nb = min(64, end - eb);               // multiple of 8
        if (nb >= 24) {                           // issue 24 before first use
            LOAD8(pa, 0)
            LOAD8(pb, 8)
            LOAD8(pc, 16)
            WACC8(pa, 0)
            WACC8(pb, 8)
            WACC8(pc, 16)
            for (int j = 24; j + 8 <= nb; j += 8) {   // deg>24 tail (~2% of nodes)
                LOAD8(pd, j)
                WACC8(pd, j)
            }
        } else if (nb == 16) {
            LOAD8(pe, 0)
            LOAD8(pf, 8)
            WACC8(pe, 0)
            WACC8(pf, 8)
        } else {
            LOAD8(pg, 0)
            WACC8(pg, 0)
        }
    }
    float2 bi = ((const float2*)bias)[lane];
    float2 ga = ((const float2*)gamma)[lane];
    float2 be = ((const float2*)beta)[lane];
    float vx = ax * di + bi.x;
    float vy = ay * di + bi.y;
    float sum = vx + vy, sq = vx * vx + vy * vy;
#pragma unroll
    for (int off = 32; off > 0; off >>= 1) {
        sum += __shfl_xor(sum, off, 64);
        sq += __shfl_xor(sq, off, 64);
    }
    float mu = sum * (1.0f / 128.0f);
    float var = sq * (1.0f / 128.0f) - mu * mu;
    float rstd = rsqrtf(var + LN_EPS);
    float o0 = fmaxf((vx - mu) * rstd * ga.x + be.x, 0.f);
    float o1 = fmaxf((vy - mu) * rstd * ga.y + be.y, 0.f);
    ((float2*)out)[(size_t)wid * 64 + lane] = make_float2(o0, o1);
}

extern "C" void kernel_launch(void* const* d_in, const int* in_sizes, int n_in,
                              void* d_out, int out_size, void* d_ws, size_t ws_size,
                              hipStream_t stream) {
    const float* x = (const float*)d_in[0];
    const int* ei = (const int*)d_in[1];
    const float* W = (const float*)d_in[2];
    const float* bias = (const float*)d_in[3];
    const float* gamma = (const float*)d_in[4];
    const float* beta = (const float*)d_in[5];
    float* out = (float*)d_out;

    int N = in_sizes[0] / 128;
    int E = in_sizes[1] / 2;
    int NBUCK = (N + 127) / 128;                 // 128-node buckets (782)

    char* p = (char*)d_ws;
    auto alloc = [&](size_t bytes) {
        char* r = p;
        p += (bytes + 255) & ~(size_t)255;
        return r;
    };
    int* bucketCnt = (int*)alloc(MAXBUCK * 4);
    int2* rowcnt = (int2*)alloc((size_t)N * 8);
    float* dinv = (float*)alloc((size_t)(N + 1) * 4);            // +1: dinv[N]=0 pad weight
    __hip_bfloat16* Wt = (__hip_bfloat16*)alloc(128 * 128 * 2);
    int* srcidx = (int*)alloc(((size_t)NBUCK * CAP + 64) * 4);   // +64 ints slack for prefetch over-read
    __hip_bfloat16* gbuf = (__hip_bfloat16*)alloc((size_t)(N + 1) * 128 * 2);  // +1 dummy zero row
    unsigned* pk = (unsigned*)d_out;             // pk lives in d_out (12.8MB <= 51.2MB); dead before agg writes out

    int chunk = (E + NPBLK - 1) / NPBLK;         // 2778 <= 2816 LDS buffer
    int GB = (N + 127) / 128;

    k_init<<<64, 256, 0, stream>>>(W, Wt, bucketCnt, (unsigned*)(gbuf + (size_t)N * 128), dinv, N);
    k_part_gemm<<<NPBLK + GB, 256, 0, stream>>>(ei, bucketCnt, pk, E, chunk, x, Wt, gbuf, N);
    k_csr<<<NBUCK, 512, 0, stream>>>(pk, bucketCnt, rowcnt, dinv, srcidx, N);
    k_agg_ln<<<(N + 3) / 4, 256, 0, stream>>>(gbuf, srcidx, rowcnt, dinv, bias, gamma, beta, out, N);
}